// Round 1
// baseline (1918.622 us; speedup 1.0000x reference)
//
#include <hip/hip_runtime.h>

// Problem constants (T,B,H,K,Q from the reference)
constexpr int NB = 32;    // batch
constexpr int NT = 2048;  // time
constexpr int NK = 1024;  // encoder hidden
constexpr int NH = 1024;  // attn hidden
constexpr int NQ = 1024;  // decoder hidden
constexpr int NTB = NT * NB;  // 65536 rows of encoder_hidden viewed as (T*B, K)

// ---------------------------------------------------------------------------
// Kernel 1: query[b][h] = sum_q dec[b][q] * Wq[h][q]   (tiny: 67 MFLOP)
// grid (NB, NH/64), 256 threads. Each h handled by 4 threads.
// ---------------------------------------------------------------------------
__global__ __launch_bounds__(256)
void query_kernel(const float* __restrict__ dec, const float* __restrict__ Wq,
                  float* __restrict__ query) {
  int b = blockIdx.x;
  int h0 = blockIdx.y * 64;
  __shared__ float sdec[NQ];
  for (int i = threadIdx.x; i < NQ; i += 256) sdec[i] = dec[b * NQ + i];
  __syncthreads();
  int hl = threadIdx.x >> 2;   // 0..63
  int p  = threadIdx.x & 3;    // 0..3
  int h = h0 + hl;
  const float* wrow = Wq + (size_t)h * NQ;
  float s = 0.f;
  for (int k = p * 4; k < NQ; k += 16) {
    float4 w = *(const float4*)(wrow + k);
    float4 d = *(const float4*)(sdec + k);
    s += w.x * d.x + w.y * d.y + w.z * d.z + w.w * d.w;
  }
  s += __shfl_xor(s, 1);
  s += __shfl_xor(s, 2);
  if (p == 0) query[b * NH + h] = s;
}

// ---------------------------------------------------------------------------
// Kernel 2: fused proj_key GEMM + tanh + dot-with-v partial scores.
// C[r][h] = sum_k E[r][k] * Wk[h][k],  r = t*NB + b
// score[r] += sum_{h in tile} tanh(query[b][h] + C[r][h]) * v[h]  (atomicAdd)
// Tile: 64 rows x 64 h, 256 threads (16x16), 4x4 regs/thread, KK=32 chunks.
// grid.x = (NTB/64) * (NH/64); h-tile is the fast index (E-tile L2 reuse).
// ---------------------------------------------------------------------------
__global__ __launch_bounds__(256)
void scores_kernel(const float* __restrict__ E, const float* __restrict__ Wk,
                   const float* __restrict__ query, const float* __restrict__ v,
                   float* __restrict__ scores) {
  const int bx = blockIdx.x;
  const int ht = bx & 15;   // NH/64 = 16
  const int rt = bx >> 4;
  const int rowBase = rt * 64;
  const int hBase = ht * 64;

  __shared__ float lse[32][68];  // [k][row], padded for b128 alignment
  __shared__ float lsw[32][68];  // [k][h]

  const int tid = threadIdx.x;
  const int tx = tid & 15;   // h group
  const int ty = tid >> 4;   // row group

  float acc[4][4] = {};

  const int rowL = tid >> 3;        // 0..31
  const int kq   = (tid & 7) << 2;  // 0,4,...,28

  for (int k0 = 0; k0 < NK; k0 += 32) {
    if (k0) __syncthreads();
    // stage 64x32 E-tile and 64x32 Wk-tile, transposed to k-major
    const float* Ebase = E  + (size_t)rowBase * NK + k0 + kq;
    const float* Wbase = Wk + (size_t)hBase  * NK + k0 + kq;
#pragma unroll
    for (int rr = 0; rr < 2; ++rr) {
      int r = rowL + rr * 32;
      float4 eg = *(const float4*)(Ebase + (size_t)r * NK);
      lse[kq + 0][r] = eg.x; lse[kq + 1][r] = eg.y;
      lse[kq + 2][r] = eg.z; lse[kq + 3][r] = eg.w;
      float4 wg = *(const float4*)(Wbase + (size_t)r * NK);
      lsw[kq + 0][r] = wg.x; lsw[kq + 1][r] = wg.y;
      lsw[kq + 2][r] = wg.z; lsw[kq + 3][r] = wg.w;
    }
    __syncthreads();

#pragma unroll 8
    for (int kk = 0; kk < 32; ++kk) {
      float4 av = *(const float4*)(&lse[kk][ty << 2]);
      float4 bv = *(const float4*)(&lsw[kk][tx << 2]);
      float a[4] = {av.x, av.y, av.z, av.w};
      float bb[4] = {bv.x, bv.y, bv.z, bv.w};
#pragma unroll
      for (int i = 0; i < 4; ++i)
#pragma unroll
        for (int j = 0; j < 4; ++j)
          acc[i][j] = fmaf(a[i], bb[j], acc[i][j]);
    }
  }

  // epilogue: tanh + v-dot over this h-tile, reduce over tx, atomic partial
  const int h0 = hBase + (tx << 2);
  const float4 vv = *(const float4*)(v + h0);
#pragma unroll
  for (int i = 0; i < 4; ++i) {
    int r = rowBase + (ty << 2) + i;
    int b = r & (NB - 1);   // r % 32
    float4 qv = *(const float4*)(query + b * NH + h0);
    float s = tanhf(acc[i][0] + qv.x) * vv.x
            + tanhf(acc[i][1] + qv.y) * vv.y
            + tanhf(acc[i][2] + qv.z) * vv.z
            + tanhf(acc[i][3] + qv.w) * vv.w;
    s += __shfl_xor(s, 1);
    s += __shfl_xor(s, 2);
    s += __shfl_xor(s, 4);
    s += __shfl_xor(s, 8);
    if (tx == 0) atomicAdd(&scores[r], s);
  }
}

// ---------------------------------------------------------------------------
// Kernel 3: masked softmax over t, per b.  In-place on scores->alphas.
// grid NB, 256 threads; each thread owns 8 t's.
// ---------------------------------------------------------------------------
__global__ __launch_bounds__(256)
void softmax_kernel(const int* __restrict__ mask, float* __restrict__ alphas) {
  int b = blockIdx.x;
  int tid = threadIdx.x;
  float sv[8];
  int mv[8];
  float mx = -INFINITY;
#pragma unroll
  for (int i = 0; i < 8; ++i) {
    int t = tid + i * 256;
    sv[i] = alphas[t * NB + b];
    mv[i] = mask[t * NB + b];
    if (mv[i] != 0) mx = fmaxf(mx, sv[i]);
  }
  __shared__ float red[256];
  red[tid] = mx;
  __syncthreads();
  for (int o = 128; o > 0; o >>= 1) {
    if (tid < o) red[tid] = fmaxf(red[tid], red[tid + o]);
    __syncthreads();
  }
  mx = red[0];
  __syncthreads();
  float sum = 0.f;
#pragma unroll
  for (int i = 0; i < 8; ++i) {
    if (mv[i] != 0) { sv[i] = expf(sv[i] - mx); sum += sv[i]; }
    else sv[i] = 0.f;
  }
  red[tid] = sum;
  __syncthreads();
  for (int o = 128; o > 0; o >>= 1) {
    if (tid < o) red[tid] += red[tid + o];
    __syncthreads();
  }
  float inv = 1.f / red[0];
#pragma unroll
  for (int i = 0; i < 8; ++i) {
    int t = tid + i * 256;
    alphas[t * NB + b] = sv[i] * inv;
  }
}

// ---------------------------------------------------------------------------
// Kernel 4: context[b][k] = sum_t alphas[t][b] * E[t][b][k]
// grid (NK/256, NB, NT/128), 256 threads; coalesced 1KB row reads; atomics.
// ---------------------------------------------------------------------------
__global__ __launch_bounds__(256)
void context_kernel(const float* __restrict__ E, const float* __restrict__ alphas,
                    float* __restrict__ ctx) {
  int k = blockIdx.x * 256 + threadIdx.x;
  int b = blockIdx.y;
  int t0 = blockIdx.z * 128;
  float acc = 0.f;
  for (int t = t0; t < t0 + 128; ++t) {
    float a = alphas[t * NB + b];
    acc = fmaf(a, E[((size_t)t * NB + b) * NK + k], acc);
  }
  atomicAdd(&ctx[b * NK + k], acc);
}

// ---------------------------------------------------------------------------
extern "C" void kernel_launch(void* const* d_in, const int* in_sizes, int n_in,
                              void* d_out, int out_size, void* d_ws, size_t ws_size,
                              hipStream_t stream) {
  const float* dec  = (const float*)d_in[0];  // (1,B,Q)
  const float* enc  = (const float*)d_in[1];  // (T,B,K)
  const int*   mask = (const int*)d_in[2];    // (T,B)
  const float* Wk   = (const float*)d_in[3];  // (H,K)
  const float* Wq   = (const float*)d_in[4];  // (H,Q)
  const float* v    = (const float*)d_in[5];  // (H,)

  float* ctx    = (float*)d_out;              // B*K
  float* alphas = (float*)d_out + NB * NK;    // T*B (used as scores first)
  float* query  = (float*)d_ws;               // B*H floats (128 KB)

  // zero context + scores (atomics accumulate into both)
  hipMemsetAsync(d_out, 0, (size_t)out_size * sizeof(float), stream);

  query_kernel<<<dim3(NB, NH / 64), 256, 0, stream>>>(dec, Wq, query);
  scores_kernel<<<dim3((NTB / 64) * (NH / 64)), 256, 0, stream>>>(enc, Wk, query, v, alphas);
  softmax_kernel<<<dim3(NB), 256, 0, stream>>>(mask, alphas);
  context_kernel<<<dim3(NK / 256, NB, NT / 128), 256, 0, stream>>>(enc, alphas, ctx);
}

// Round 2
// 494.844 us; speedup vs baseline: 3.8772x; 3.8772x over previous
//
#include <hip/hip_runtime.h>

constexpr int NB = 32;    // batch
constexpr int NT = 2048;  // time
constexpr int NK = 1024;  // encoder hidden (K of GEMM)
constexpr int NH = 1024;  // attn hidden (N of GEMM)
constexpr int NQ = 1024;  // decoder hidden
constexpr int NTB = NT * NB;  // 65536 GEMM rows

typedef __attribute__((ext_vector_type(8))) short bf16x8;
typedef __attribute__((ext_vector_type(4))) float f32x4;

__device__ __forceinline__ short f2bf(float f) {
  union { float f; unsigned u; } c{f};
  unsigned r = (c.u + 0x7fffu + ((c.u >> 16) & 1u)) >> 16;
  return (short)r;
}

// ---------------------------------------------------------------------------
// Kernel 1: query[b][h] = sum_q dec[b][q] * Wq[h][q]  (fp32, tiny)
// ---------------------------------------------------------------------------
__global__ __launch_bounds__(256)
void query_kernel(const float* __restrict__ dec, const float* __restrict__ Wq,
                  float* __restrict__ query) {
  int b = blockIdx.x;
  int h0 = blockIdx.y * 64;
  __shared__ float sdec[NQ];
  for (int i = threadIdx.x; i < NQ; i += 256) sdec[i] = dec[b * NQ + i];
  __syncthreads();
  int hl = threadIdx.x >> 2;
  int p  = threadIdx.x & 3;
  int h = h0 + hl;
  const float* wrow = Wq + (size_t)h * NQ;
  float s = 0.f;
  for (int k = p * 4; k < NQ; k += 16) {
    float4 w = *(const float4*)(wrow + k);
    float4 d = *(const float4*)(sdec + k);
    s += w.x * d.x + w.y * d.y + w.z * d.z + w.w * d.w;
  }
  s += __shfl_xor(s, 1);
  s += __shfl_xor(s, 2);
  if (p == 0) query[b * NH + h] = s;
}

// ---------------------------------------------------------------------------
// Kernel 2: bf16-MFMA proj_key GEMM + fused tanh/v-dot partial scores.
// C[r][h] = sum_k E[r][k]*Wk[h][k]; score[r] += sum_h tanh(C+q[b][h])*v[h]
// 128x128 tile, 4 waves (2x2 of 64x64), mfma_f32_16x16x32_bf16, BK=64.
// LDS rows padded to 72 shorts (144B = 9*16B: b128-aligned, conflict-free-ish).
// Block swizzle: all 8 h-tiles of one r-tile land on one XCD (bid%8 == rt%8).
// ---------------------------------------------------------------------------
__global__ __launch_bounds__(256)
void scores_kernel(const float* __restrict__ E, const float* __restrict__ Wk,
                   const float* __restrict__ query, const float* __restrict__ v,
                   float* __restrict__ scores) {
  // swizzle: x = bid%8 -> XCD; within an XCD, ht cycles fast so the 8 blocks
  // sharing an E row-tile are consecutive on that XCD (L2 reuse of E-tile).
  const int bid = blockIdx.x;
  const int x  = bid & 7;
  const int ht = (bid >> 3) & 7;          // NH/128 = 8
  const int rt = x + ((bid >> 6) << 3);   // 0..511
  const int rowBase = rt * 128;
  const int hBase   = ht * 128;

  __shared__ short lA[128][72];  // 128 rows x BK=64 (+8 pad), 18 KB
  __shared__ short lB[128][72];

  const int tid = threadIdx.x;
  const int lane = tid & 63;
  const int l15 = lane & 15;
  const int lhi = lane >> 4;
  const int wid = tid >> 6;      // 4 waves
  const int wm = wid >> 1;       // row half
  const int wn = wid & 1;        // col half

  // staging coords: thread covers rows rq, rq+32, rq+64, rq+96 at k-span kq..kq+7
  const int rq = tid >> 3;        // 0..31
  const int kq = (tid & 7) << 3;  // 0,8,...,56

  f32x4 acc[4][4] = {};

  for (int k0 = 0; k0 < NK; k0 += 64) {
    __syncthreads();
#pragma unroll
    for (int q = 0; q < 4; ++q) {
      int r = rq + q * 32;
      const float* pe = E  + (size_t)(rowBase + r) * NK + k0 + kq;
      const float* pw = Wk + (size_t)(hBase  + r) * NK + k0 + kq;
      float4 e0 = *(const float4*)(pe);
      float4 e1 = *(const float4*)(pe + 4);
      float4 w0 = *(const float4*)(pw);
      float4 w1 = *(const float4*)(pw + 4);
      bf16x8 se, sw;
      se[0] = f2bf(e0.x); se[1] = f2bf(e0.y); se[2] = f2bf(e0.z); se[3] = f2bf(e0.w);
      se[4] = f2bf(e1.x); se[5] = f2bf(e1.y); se[6] = f2bf(e1.z); se[7] = f2bf(e1.w);
      sw[0] = f2bf(w0.x); sw[1] = f2bf(w0.y); sw[2] = f2bf(w0.z); sw[3] = f2bf(w0.w);
      sw[4] = f2bf(w1.x); sw[5] = f2bf(w1.y); sw[6] = f2bf(w1.z); sw[7] = f2bf(w1.w);
      *(bf16x8*)&lA[r][kq] = se;
      *(bf16x8*)&lB[r][kq] = sw;
    }
    __syncthreads();

#pragma unroll
    for (int ks = 0; ks < 2; ++ks) {
      const int kk = ks * 32 + lhi * 8;
      bf16x8 af[4], bfr[4];
#pragma unroll
      for (int m = 0; m < 4; ++m)
        af[m] = *(const bf16x8*)&lA[wm * 64 + m * 16 + l15][kk];
#pragma unroll
      for (int n = 0; n < 4; ++n)
        bfr[n] = *(const bf16x8*)&lB[wn * 64 + n * 16 + l15][kk];
#pragma unroll
      for (int m = 0; m < 4; ++m)
#pragma unroll
        for (int n = 0; n < 4; ++n)
          acc[m][n] = __builtin_amdgcn_mfma_f32_16x16x32_bf16(af[m], bfr[n], acc[m][n], 0, 0, 0);
    }
  }

  // epilogue: tanh + v-dot, reduce over the 16 col-lanes, atomic partial score
  // C/D layout: col = lane&15, row = (lane>>4)*4 + reg  [m89-verified]
#pragma unroll
  for (int m = 0; m < 4; ++m) {
#pragma unroll
    for (int reg = 0; reg < 4; ++reg) {
      int row = rowBase + wm * 64 + m * 16 + lhi * 4 + reg;
      int b = row & (NB - 1);
      float s = 0.f;
#pragma unroll
      for (int n = 0; n < 4; ++n) {
        int col = hBase + wn * 64 + n * 16 + l15;
        float c = acc[m][n][reg];
        s += tanhf(c + query[b * NH + col]) * v[col];
      }
      s += __shfl_xor(s, 1);
      s += __shfl_xor(s, 2);
      s += __shfl_xor(s, 4);
      s += __shfl_xor(s, 8);
      if (l15 == 0) atomicAdd(&scores[row], s);
    }
  }
}

// ---------------------------------------------------------------------------
// Kernel 3: masked softmax over t, per b.  In-place scores -> alphas.
// ---------------------------------------------------------------------------
__global__ __launch_bounds__(256)
void softmax_kernel(const int* __restrict__ mask, float* __restrict__ alphas) {
  int b = blockIdx.x;
  int tid = threadIdx.x;
  float sv[8];
  int mv[8];
  float mx = -INFINITY;
#pragma unroll
  for (int i = 0; i < 8; ++i) {
    int t = tid + i * 256;
    sv[i] = alphas[t * NB + b];
    mv[i] = mask[t * NB + b];
    if (mv[i] != 0) mx = fmaxf(mx, sv[i]);
  }
  __shared__ float red[256];
  red[tid] = mx;
  __syncthreads();
  for (int o = 128; o > 0; o >>= 1) {
    if (tid < o) red[tid] = fmaxf(red[tid], red[tid + o]);
    __syncthreads();
  }
  mx = red[0];
  __syncthreads();
  float sum = 0.f;
#pragma unroll
  for (int i = 0; i < 8; ++i) {
    if (mv[i] != 0) { sv[i] = expf(sv[i] - mx); sum += sv[i]; }
    else sv[i] = 0.f;
  }
  red[tid] = sum;
  __syncthreads();
  for (int o = 128; o > 0; o >>= 1) {
    if (tid < o) red[tid] += red[tid + o];
    __syncthreads();
  }
  float inv = 1.f / red[0];
#pragma unroll
  for (int i = 0; i < 8; ++i) {
    int t = tid + i * 256;
    alphas[t * NB + b] = sv[i] * inv;
  }
}

// ---------------------------------------------------------------------------
// Kernel 4: context[b][k] = sum_t alphas[t][b] * E[t][b][k]
// ---------------------------------------------------------------------------
__global__ __launch_bounds__(256)
void context_kernel(const float* __restrict__ E, const float* __restrict__ alphas,
                    float* __restrict__ ctx) {
  int k = blockIdx.x * 256 + threadIdx.x;
  int b = blockIdx.y;
  int t0 = blockIdx.z * 128;
  float acc = 0.f;
  for (int t = t0; t < t0 + 128; ++t) {
    float a = alphas[t * NB + b];
    acc = fmaf(a, E[((size_t)t * NB + b) * NK + k], acc);
  }
  atomicAdd(&ctx[b * NK + k], acc);
}

// ---------------------------------------------------------------------------
extern "C" void kernel_launch(void* const* d_in, const int* in_sizes, int n_in,
                              void* d_out, int out_size, void* d_ws, size_t ws_size,
                              hipStream_t stream) {
  const float* dec  = (const float*)d_in[0];
  const float* enc  = (const float*)d_in[1];
  const int*   mask = (const int*)d_in[2];
  const float* Wk   = (const float*)d_in[3];
  const float* Wq   = (const float*)d_in[4];
  const float* v    = (const float*)d_in[5];

  float* ctx    = (float*)d_out;
  float* alphas = (float*)d_out + NB * NK;
  float* query  = (float*)d_ws;   // B*H fp32

  hipMemsetAsync(d_out, 0, (size_t)out_size * sizeof(float), stream);

  query_kernel<<<dim3(NB, NH / 64), 256, 0, stream>>>(dec, Wq, query);
  scores_kernel<<<dim3((NTB / 128) * (NH / 128)), 256, 0, stream>>>(enc, Wk, query, v, alphas);
  softmax_kernel<<<dim3(NB), 256, 0, stream>>>(mask, alphas);
  context_kernel<<<dim3(NK / 256, NB, NT / 128), 256, 0, stream>>>(enc, alphas, ctx);
}